// Round 1
// baseline (236.185 us; speedup 1.0000x reference)
//
#include <hip/hip_runtime.h>
#include <stdint.h>

#define VV 128000
#define BLOCK 1024
#define NB 4096
#define CAP 4096
#define THR 2.0f
#define U0  0xC0000000u   /* fkey(2.0f) */
#define MSEL 2048

typedef unsigned long long ull;

__device__ __forceinline__ uint32_t rotl32(uint32_t x, int r){ return (x << r) | (x >> (32 - r)); }

// Bit-exact replica of jax.random.exponential(key(42), (256,128000), f32) at flat
// index f, under jax_threefry_partitionable=True: per element,
// threefry2x32(key, counter=(hi32(i), lo32(i))), bits = out0 ^ out1.
__device__ __forceinline__ float exp_noise(uint32_t f){
  const uint32_t ks0 = 0u, ks1 = 42u, ks2 = 0x1BD11BDAu ^ 0u ^ 42u;
  uint32_t x0 = 0u + ks0;
  uint32_t x1 = f + ks1;
#define R1(r) { x0 += x1; x1 = rotl32(x1, r); x1 ^= x0; }
  R1(13) R1(15) R1(26) R1(6)   x0 += ks1; x1 += ks2 + 1u;
  R1(17) R1(29) R1(16) R1(24)  x0 += ks2; x1 += ks0 + 2u;
  R1(13) R1(15) R1(26) R1(6)   x0 += ks0; x1 += ks1 + 3u;
  R1(17) R1(29) R1(16) R1(24)  x0 += ks1; x1 += ks2 + 4u;
  R1(13) R1(15) R1(26) R1(6)   x0 += ks2; x1 += ks0 + 5u;
#undef R1
  uint32_t bits = x0 ^ x1;
  float u = __uint_as_float((bits >> 9) | 0x3F800000u) - 1.0f;
  float e = -log1pf(-u);
  return fmaxf(e, 1e-10f);
}

// ascending-order key: larger float -> larger key (total order; no NaN in input)
__device__ __forceinline__ uint32_t fkey(float x){
  uint32_t u = __float_as_uint(x);
  return u ^ ((u & 0x80000000u) ? 0xFFFFFFFFu : 0x80000000u);
}
__device__ __forceinline__ float keyval(uint32_t k){
  uint32_t bits = (k & 0x80000000u) ? (k ^ 0x80000000u) : ~k;
  return __uint_as_float(bits);
}

// In-place inclusive suffix sum over NB=4096 entries (4 per thread + Hillis-Steele).
__device__ void suffix_scan_u(uint32_t* h, uint32_t* tmp, int tid){
  const int base = tid * 4;
  uint32_t l0=h[base], l1=h[base+1], l2=h[base+2], l3=h[base+3];
  uint32_t s3=l3, s2=l2+s3, s1=l1+s2, s0=l0+s1;
  tmp[tid] = s0; __syncthreads();
  for (int d=1; d<BLOCK; d<<=1){
    uint32_t add = (tid+d<BLOCK) ? tmp[tid+d] : 0u;
    __syncthreads();
    tmp[tid] += add;
    __syncthreads();
  }
  uint32_t E = (tid+1<BLOCK) ? tmp[tid+1] : 0u;
  h[base]=s0+E; h[base+1]=s1+E; h[base+2]=s2+E; h[base+3]=s3+E;
  __syncthreads();
}
__device__ void suffix_scan_f(float* h, float* tmp, int tid){
  const int base = tid * 4;
  float l0=h[base], l1=h[base+1], l2=h[base+2], l3=h[base+3];
  float s3=l3, s2=l2+s3, s1=l1+s2, s0=l0+s1;
  tmp[tid] = s0; __syncthreads();
  for (int d=1; d<BLOCK; d<<=1){
    float add = (tid+d<BLOCK) ? tmp[tid+d] : 0.f;
    __syncthreads();
    tmp[tid] += add;
    __syncthreads();
  }
  float E = (tid+1<BLOCK) ? tmp[tid+1] : 0.f;
  h[base]=s0+E; h[base+1]=s1+E; h[base+2]=s2+E; h[base+3]=s3+E;
  __syncthreads();
}

// tid0-serial: move the t smallest of a[0..n) to front, return t-th smallest.
__device__ uint32_t select_tth_smallest(uint32_t* a, int n, int t){
  for (int i=0;i<t;i++){
    int mi=i; uint32_t mv=a[i];
    for (int j=i+1;j<n;j++) if (a[j]<mv){ mv=a[j]; mi=j; }
    a[mi]=a[i]; a[i]=mv;
  }
  return a[t-1];
}

// bitonic ascending on packed (~key, idx): value desc, idx asc (stable argsort(-x))
__device__ void bitonic_sort(ull* a, int N, int tid){
  for (int len=2; len<=N; len<<=1){
    for (int j=len>>1; j>0; j>>=1){
      for (int i=tid; i<N; i+=BLOCK){
        int l = i ^ j;
        if (l > i){
          ull x = a[i], y = a[l];
          bool asc = ((i & len) == 0);
          if (asc ? (x > y) : (x < y)){ a[i]=y; a[l]=x; }
        }
      }
      __syncthreads();
    }
  }
}

// Raw-key row loop (no division): u = fkey(raw logit).
#define ROW4R_BEGIN \
    for (int c0 = tid; c0 < VV/4; c0 += BLOCK*4){ \
      float4 qv[4]; int cb[4]; bool gv[4]; \
      _Pragma("unroll") \
      for (int t=0;t<4;t++){ int cc = c0 + t*BLOCK; gv[t] = (cc < VV/4); cb[t] = cc*4; if (gv[t]) qv[t] = rp[cc]; } \
      _Pragma("unroll") \
      for (int t=0;t<4;t++) if (gv[t]){ \
        float vs[4] = {qv[t].x, qv[t].y, qv[t].z, qv[t].w}; \
        _Pragma("unroll") \
        for (int j=0;j<4;j++){ \
          uint32_t u = fkey(vs[j]); \
          uint32_t idx = (uint32_t)(cb[t]+j); \
          (void)idx;
#define ROW4R_END } } }

// x-key row loop (exact x = v/T), for the slow (k==0 / overflow) path.
#define ROW4_BEGIN \
    for (int c0 = tid; c0 < VV/4; c0 += BLOCK*4){ \
      float4 qv[4]; int cb[4]; bool gv[4]; \
      _Pragma("unroll") \
      for (int t=0;t<4;t++){ int cc = c0 + t*BLOCK; gv[t] = (cc < VV/4); cb[t] = cc*4; if (gv[t]) qv[t] = rp[cc]; } \
      _Pragma("unroll") \
      for (int t=0;t<4;t++) if (gv[t]){ \
        float xs[4] = {qv[t].x, qv[t].y, qv[t].z, qv[t].w}; \
        _Pragma("unroll") \
        for (int j=0;j<4;j++){ \
          float x = xs[j]/T; \
          uint32_t u = fkey(x); \
          uint32_t idx = (uint32_t)(cb[t]+j); \
          (void)idx;
#define ROW4_END } } }

__global__ __launch_bounds__(BLOCK) void sampler_kernel(
    const float* __restrict__ logits, const float* __restrict__ temps,
    const int* __restrict__ topks, const float* __restrict__ topps,
    int* __restrict__ out)
{
  // Carved shared memory (102400 B):
  //  NEW fast path overlay: gcand ull[4096] @0 (32K), hc u32[4096] @32K (16K),
  //                         sel ull[2048] @48K (16K)
  //  OLD fast path: h4 u32[16384] @0 (64K) | cand ull[4096] @0, h2 @32K, sort2 @48K
  //  slow path: S f[4096] @0, wf f[4096] @16K
  //  [64K,80K) wu u32[4096]
  //  [80K,84K) tmpf f[1024]; [84K,88K) tmpu u32[1024];
  //  [88K,92K) ck f[1024];   [92K,100K) red ull[1024]
  // (Overlays are safe: every consumer initializes its region before reading.)
  __shared__ __align__(16) uint8_t SM[102400];
  uint32_t* h4    = (uint32_t*)SM;
  ull*      cand  = (ull*)SM;
  uint32_t* h2    = (uint32_t*)(SM + 32*1024);
  ull*      sort2 = (ull*)(SM + 48*1024);
  ull*      gcand = (ull*)SM;
  uint32_t* hc    = (uint32_t*)(SM + 32*1024);
  ull*      sel   = (ull*)(SM + 48*1024);
  float*    S     = (float*)SM;
  float*    wf    = (float*)(SM + 16*1024);
  uint32_t* wu    = (uint32_t*)(SM + 64*1024);
  float*    tmpf  = (float*)(SM + 80*1024);
  uint32_t* tmpu  = (uint32_t*)(SM + 84*1024);
  float*    ck    = (float*)(SM + 88*1024);
  ull*      red   = (ull*)(SM + 92*1024);

  __shared__ int s_idx, s_n, s_n2, s_tk, s_ntk, s_tp, s_ntp, s_nf, s_ns;
  __shared__ uint32_t s_uk, s_idxk, s_up, s_idxp;
  __shared__ float s_m, s_Zk, s_Ztot;
  __shared__ ull s_K0;

  const int b   = blockIdx.x;
  const int tid = threadIdx.x;
  const float T = temps[b];
  const int   k = topks[b];
  const float p = topps[b];
  const float* row = logits + (size_t)b * VV;
  const float4* rp = reinterpret_cast<const float4*>(row);
  const bool topk_act = (k > 0) && (k < VV);
  const bool topp_act = (p > 0.0f) && (p < 1.0f);

  // ============================================================================
  // NEW FAST PATH: single-pass threshold gather (v >= 2.0) + exact integer prune
  // + barrier-free rank loop. Numerically identical epilogue to the verified
  // sort-based path (values scattered into ck[]/red[] by rank). Exact fallback
  // to the old machinery whenever the statistical gate fails.
  // ============================================================================
  if (topk_act){
    {
      if (tid==0) s_nf = 0;
      __syncthreads();
      // ---- pass 1: stream row, gather candidates with raw v >= THR ----
      for (int c0 = tid; c0 < VV/4; c0 += BLOCK*4){
        float4 qv[4]; int cb[4]; bool gvv[4];
        #pragma unroll
        for (int t=0;t<4;t++){ int cc=c0+t*BLOCK; gvv[t]=(cc<VV/4); cb[t]=cc*4; if(gvv[t]) qv[t]=rp[cc]; }
        #pragma unroll
        for (int t=0;t<4;t++) if (gvv[t]){
          float vsx[4]={qv[t].x,qv[t].y,qv[t].z,qv[t].w};
          #pragma unroll
          for (int j=0;j<4;j++){
            if (vsx[j] >= THR){
              int pos = atomicAdd(&s_nf, 1);
              if (pos < CAP) gcand[pos] = (((ull)fkey(vsx[j]))<<32) | (ull)(uint32_t)(cb[t]+j);
            }
          }
        }
      }
      __syncthreads();
      const int nf = s_nf;
      bool ok = (nf >= k) && (nf <= CAP) && (k <= BLOCK);
      int m = 0; uint32_t gam = 0u;
      if (ok){
        // ---- prune: 4096-bin histogram over candidates only (integer-exact) ----
        for (int i=tid;i<NB;i+=BLOCK) hc[i]=0u;
        __syncthreads();
        for (int i=tid;i<nf;i+=BLOCK){
          uint32_t u2 = (uint32_t)(gcand[i]>>32);
          uint32_t bu = (u2 - U0) >> 12; if (bu > 4095u) bu = 4095u;
          atomicAdd(&hc[bu], 1u);
        }
        __syncthreads();
        suffix_scan_u(hc, tmpu, tid);
        if (tid==0) s_idx = 0;
        __syncthreads();
        for (int i=tid;i<NB;i+=BLOCK){
          uint32_t a  = hc[i];
          uint32_t nn = (i+1<NB) ? hc[i+1] : 0u;
          if (a >= (uint32_t)k && nn < (uint32_t)k) s_idx = i;
        }
        __syncthreads();
        gam = (uint32_t)s_idx;
        m = (int)hc[gam];               // exact survivor count, >= k
        ok = (m <= MSEL);
      }
      if (ok){
        // ---- compact survivors, packed K = (u<<32) | ~idx (desc value, asc idx) ----
        if (tid==0) s_ns = 0;
        __syncthreads();
        for (int i=tid;i<nf;i+=BLOCK){
          ull e = gcand[i];
          uint32_t u2 = (uint32_t)(e>>32);
          uint32_t bu = (u2 - U0) >> 12; if (bu > 4095u) bu = 4095u;
          if (bu >= gam){
            int pos = atomicAdd(&s_ns, 1);
            sel[pos] = (e & 0xFFFFFFFF00000000ull) | (ull)(~(uint32_t)e);
          }
        }
        __syncthreads();
        // ---- barrier-free rank loop (replaces the 55-phase bitonic sort) ----
        ull K0 = (tid < m)       ? sel[tid]       : 0ull;
        ull K1 = (tid+BLOCK < m) ? sel[tid+BLOCK] : 0ull;
        int r0 = 0, r1 = 0;
        #pragma unroll 4
        for (int j=0;j<m;j++){
          ull Kj = sel[j];           // LDS broadcast read
          r0 += (Kj > K0);
          r1 += (Kj > K1);
        }
        if (tid < m && r0 == 0)       s_K0 = K0;
        if (tid+BLOCK < m && r1 == 0) s_K0 = K1;
        __syncthreads();
        const float xm = keyval((uint32_t)(s_K0>>32)) / T;   // row max of x
        float w0 = 0.f, w1 = 0.f;
        if (tid < m && r0 < k)       w0 = expf(keyval((uint32_t)(K0>>32))/T - xm);
        if (tid+BLOCK < m && r1 < k) w1 = expf(keyval((uint32_t)(K1>>32))/T - xm);
        // ---- Zk: scatter by rank, tree reduce (same association as old path) ----
        ck[tid] = 0.f;
        __syncthreads();
        if (tid < m && r0 < k)       ck[r0] = w0;
        if (tid+BLOCK < m && r1 < k) ck[r1] = w1;
        __syncthreads();
        for (int d=BLOCK/2; d>0; d>>=1){
          if (tid < d) ck[tid] += ck[tid+d];
          __syncthreads();
        }
        if (tid==0) s_Ztot = ck[0];
        __syncthreads();
        const float Zk = s_Ztot;
        // ---- inclusive cumsum of probs (identical H-S as old path) ----
        ck[tid] = 0.f;
        __syncthreads();
        if (tid < m && r0 < k)       ck[r0] = w0 / Zk;
        if (tid+BLOCK < m && r1 < k) ck[r1] = w1 / Zk;
        __syncthreads();
        for (int d=1; d<BLOCK; d<<=1){
          float add = (tid >= d) ? ck[tid-d] : 0.f;
          __syncthreads();
          ck[tid] += add;
          __syncthreads();
        }
        tmpu[tid] = (tid < k && ck[tid] <= p) ? 1u : 0u;
        __syncthreads();
        for (int d=BLOCK/2; d>0; d>>=1){
          if (tid < d) tmpu[tid] += tmpu[tid+d];
          __syncthreads();
        }
        int L;
        if (!topp_act) L = k;
        else { int c = (int)tmpu[0]; L = (c >= k) ? k : (c + 1); }
        // ---- Gumbel race over top-L (scatter by rank, same tree as old path) ----
        red[tid] = 0ull;
        __syncthreads();
        if (tid < m && r0 < L){
          uint32_t idx0 = ~(uint32_t)K0;
          float q = w0 / exp_noise((uint32_t)b * (uint32_t)VV + idx0);
          red[r0] = (((ull)__float_as_uint(q)) << 32) | (uint32_t)K0;
        }
        if (tid+BLOCK < m && r1 < L){
          uint32_t idx1 = ~(uint32_t)K1;
          float q = w1 / exp_noise((uint32_t)b * (uint32_t)VV + idx1);
          red[r1] = (((ull)__float_as_uint(q)) << 32) | (uint32_t)K1;
        }
        __syncthreads();
        for (int d=BLOCK/2; d>0; d>>=1){
          if (tid < d){ ull o = red[tid+d]; if (o > red[tid]) red[tid] = o; }
          __syncthreads();
        }
        if (tid==0) out[b] = (int)(~(uint32_t)(red[0] & 0xFFFFFFFFull));
        return;
      }
      __syncthreads();   // gate failed -> old verified fast path below
    }

    // ==========================================================================
    // OLD FAST PATH (k in [1,1023]) — division-free streaming on raw logit keys.
    // ==========================================================================
    for (int i=tid;i<4*NB;i+=BLOCK) h4[i]=0u;
    __syncthreads();
    ROW4R_BEGIN
      atomicAdd(&h4[((u>>20)<<2) | (uint32_t)(tid&3)], 1u);
    ROW4R_END
    __syncthreads();
    for (int i=tid;i<NB;i+=BLOCK)
      wu[i] = h4[(i<<2)] + h4[(i<<2)|1] + h4[(i<<2)|2] + h4[(i<<2)|3];
    __syncthreads();
    suffix_scan_u(wu, tmpu, tid);   // wu[i] = count of items with bucket >= i
    if (tid==0) s_idx = 0;
    __syncthreads();
    for (int i=tid;i<NB;i+=BLOCK){
      uint32_t a  = wu[i];
      uint32_t nn = (i+1<NB) ? wu[i+1] : 0u;
      if (a >= (uint32_t)k && nn < (uint32_t)k) s_idx = i;
    }
    __syncthreads();
    const uint32_t beta = (uint32_t)s_idx;
    const int n = (int)wu[beta];                          // exact, >= k
    const uint32_t c_above = (beta+1<NB) ? wu[beta+1] : 0u; // exact, < k
    if (n <= CAP){
      if (tid==0) s_n = 0;
      __syncthreads();
      ROW4R_BEGIN
        if ((u>>20) >= beta){
          int pos = atomicAdd(&s_n, 1);
          cand[pos] = (((ull)(~u))<<32) | idx;   // pos < n <= CAP guaranteed
        }
      ROW4R_END
      __syncthreads();
      // ---- prune to <=1024 entries before sorting (integer-exact) ----
      ull* srt; int m;
      if (n <= 1024){ srt = cand; m = n; }
      else {
        for (int i=tid;i<NB;i+=BLOCK) h2[i]=0u;
        __syncthreads();
        for (int i=tid;i<n;i+=BLOCK){
          uint32_t u2 = ~(uint32_t)(cand[i]>>32);
          if ((u2>>20) == beta) atomicAdd(&h2[(u2>>8)&0xFFFu], 1u);
        }
        __syncthreads();
        suffix_scan_u(h2, tmpu, tid);
        const uint32_t kr = (uint32_t)k - c_above;   // >= 1
        if (tid==0) s_idx = 0;
        __syncthreads();
        for (int i=tid;i<NB;i+=BLOCK){
          uint32_t a  = h2[i];
          uint32_t nn = (i+1<NB) ? h2[i+1] : 0u;
          if (a >= kr && nn < kr) s_idx = i;
        }
        __syncthreads();
        const uint32_t gam = (uint32_t)s_idx;
        const int np = (int)(c_above + h2[gam]);     // exact survivors, >= k
        if (np <= 1024){
          if (tid==0) s_n2 = 0;
          __syncthreads();
          const uint32_t cut24 = (beta<<12) | gam;
          for (int i=tid;i<n;i+=BLOCK){
            ull e = cand[i];
            uint32_t u2 = ~(uint32_t)(e>>32);
            if ((u2>>8) >= cut24){
              int pos = atomicAdd(&s_n2, 1);
              sort2[pos] = e;                        // pos < np guaranteed
            }
          }
          __syncthreads();
          srt = sort2; m = np;
        } else { srt = cand; m = n; }                // massive sub-bucket tie: rare
      }
      int N = 2; while (N < m) N <<= 1;
      for (int i=tid;i<N;i+=BLOCK) if (i >= m) srt[i] = 0xFFFFFFFFFFFFFFFFull;
      __syncthreads();
      bitonic_sort(srt, N, tid);
      // ---- exact top-k = first k entries; softmax over them ----
      const int kk = k;
      const float xm = keyval(~(uint32_t)(srt[0]>>32)) / T;   // row max of x
      float w = 0.f; uint32_t myidx = 0u;
      if (tid < kk){
        ull e = srt[tid];
        myidx = (uint32_t)e;
        float xv = keyval(~(uint32_t)(e>>32)) / T;
        w = expf(xv - xm);
      }
      ck[tid] = w; __syncthreads();
      for (int d=BLOCK/2; d>0; d>>=1){
        if (tid < d) ck[tid] += ck[tid+d];
        __syncthreads();
      }
      if (tid==0) s_Ztot = ck[0];
      __syncthreads();
      const float Zk = s_Ztot;
      // inclusive cumsum of probs; count cumsum <= p among first kk
      ck[tid] = w / Zk; __syncthreads();
      for (int d=1; d<BLOCK; d<<=1){
        float add = (tid >= d) ? ck[tid-d] : 0.f;
        __syncthreads();
        ck[tid] += add;
        __syncthreads();
      }
      tmpu[tid] = (tid < kk && ck[tid] <= p) ? 1u : 0u;
      __syncthreads();
      for (int d=BLOCK/2; d>0; d>>=1){
        if (tid < d) tmpu[tid] += tmpu[tid+d];
        __syncthreads();
      }
      int L;
      if (!topp_act) L = kk;
      else { int c = (int)tmpu[0]; L = (c >= kk) ? kk : (c + 1); }
      // Gumbel-race argmax over first L: argmax w_i / e_i (scale-invariant)
      ull best = 0ull;
      if (tid < L){
        float q = w / exp_noise((uint32_t)b * (uint32_t)VV + myidx);
        best = (((ull)__float_as_uint(q)) << 32) | (uint32_t)(~myidx);
      }
      red[tid] = best; __syncthreads();
      for (int d=BLOCK/2; d>0; d>>=1){
        if (tid < d){ ull o = red[tid+d]; if (o > red[tid]) red[tid] = o; }
        __syncthreads();
      }
      if (tid==0) out[b] = (int)(~(uint32_t)(red[0] & 0xFFFFFFFFull));
      return;
    }
    __syncthreads();  // n > CAP (statistically never) -> slow path
  }

  // ============================================================================
  // SLOW PATH (k==0, or fast-path overflow): round-3 verified radix machinery
  // ============================================================================
  for (int i=tid;i<NB;i+=BLOCK){ S[i]=0.f; wu[i]=0u; }
  __syncthreads();
  float lmax = -3.4e38f;
  ROW4_BEGIN
    lmax = fmaxf(lmax, x);
    atomicAdd(&wu[u>>20], 1u);
    atomicAdd(&S[u>>20], expf(x));
  ROW4_END
  tmpf[tid] = lmax; __syncthreads();
  for (int d=BLOCK/2; d>0; d>>=1){
    if (tid < d) tmpf[tid] = fmaxf(tmpf[tid], tmpf[tid+d]);
    __syncthreads();
  }
  if (tid==0) s_m = tmpf[0];
  __syncthreads();
  suffix_scan_u(wu, tmpu, tid);
  suffix_scan_f(S,  tmpf, tid);

  uint32_t uk = 0u, idxk = 0xFFFFFFFFu;
  int bk1 = -1;
  if (topk_act){
    if (tid==0) s_idx = 0;
    __syncthreads();
    for (int i=tid;i<NB;i+=BLOCK){
      uint32_t a  = wu[i];
      uint32_t nn = (i+1<NB) ? wu[i+1] : 0u;
      if (a >= (uint32_t)k && nn < (uint32_t)k) s_idx = i;
    }
    __syncthreads();
    bk1 = s_idx;
    const uint32_t c_above1 = (bk1+1<NB) ? wu[bk1+1] : 0u;
    const float    M_above1 = (bk1+1<NB) ? S[bk1+1]  : 0.f;
    __syncthreads();
    for (int i=tid;i<NB;i+=BLOCK){ wu[i]=0u; wf[i]=0.f; }
    __syncthreads();
    ROW4_BEGIN
      if ((int)(u>>20) == bk1){
        atomicAdd(&wu[(u>>8)&0xFFFu], 1u);
        atomicAdd(&wf[(u>>8)&0xFFFu], expf(x));
      }
    ROW4_END
    __syncthreads();
    suffix_scan_u(wu, tmpu, tid);
    suffix_scan_f(wf, tmpf, tid);
    if (tid==0) s_idx = 0;
    __syncthreads();
    for (int i=tid;i<NB;i+=BLOCK){
      uint32_t a  = c_above1 + wu[i];
      uint32_t nn = c_above1 + ((i+1<NB) ? wu[i+1] : 0u);
      if (a >= (uint32_t)k && nn < (uint32_t)k) s_idx = i;
    }
    __syncthreads();
    const int bk2 = s_idx;
    const uint32_t c_above2 = c_above1 + ((bk2+1<NB) ? wu[bk2+1] : 0u);
    const float    M_above2 = M_above1 + ((bk2+1<NB) ? wf[bk2+1] : 0.f);
    __syncthreads();
    if (tid < 256){ wu[tid]=0u; wf[tid]=0.f; }
    __syncthreads();
    const uint32_t top24k = (((uint32_t)bk1)<<12) | (uint32_t)bk2;
    ROW4_BEGIN
      if ((u>>8) == top24k){
        atomicAdd(&wu[u & 0xFFu], 1u);
        atomicAdd(&wf[u & 0xFFu], expf(x));
      }
    ROW4_END
    __syncthreads();
    if (tid==0){
      uint32_t r = 0u; float mr = 0.f; int b3 = 0;
      for (int i=255;i>=0;--i){
        if (c_above2 + r + wu[i] >= (uint32_t)k){ b3 = i; break; }
        r += wu[i]; mr += wf[i];
      }
      const uint32_t cgt = c_above2 + r;
      const float mgt = M_above2 + mr;
      const int nt = (int)wu[b3];
      const int tk = k - (int)cgt;
      s_uk  = (((uint32_t)bk1)<<20) | (((uint32_t)bk2)<<8) | (uint32_t)b3;
      s_tk  = tk; s_ntk = nt;
      s_Zk  = mgt + (float)tk * expf(keyval(s_uk));
      s_n   = 0;
    }
    __syncthreads();
    uk = s_uk;
    if (s_tk < s_ntk){
      ROW4_BEGIN
        if (u == uk){
          int pos = atomicAdd(&s_n, 1);
          if (pos < NB) wu[pos] = idx;
        }
      ROW4_END
      __syncthreads();
      if (tid==0){
        int n2 = min(s_n, NB);
        int t  = min(s_tk, n2);
        s_idxk = select_tth_smallest(wu, n2, t);
      }
      __syncthreads();
      idxk = s_idxk;
    }
  }
  const float Zk = topk_act ? s_Zk : S[0];

  uint32_t up = 0u, idxp = 0xFFFFFFFFu;
  const float tgt = p * Zk;
  const bool pall = (!topp_act) || (tgt >= Zk);
  if (!pall){
    if (tid==0) s_idx = -2;
    __syncthreads();
    for (int i=tid;i<NB;i+=BLOCK){
      if (i > bk1){
        float a  = S[i];
        float nn = (i+1<NB) ? S[i+1] : 0.f;
        if (a > tgt && nn <= tgt) s_idx = i;
      }
    }
    __syncthreads();
    int bp1 = (s_idx >= 0) ? s_idx : bk1;
    if (bp1 < 0) bp1 = 0;
    const float Mab = (bp1+1<NB) ? S[bp1+1] : 0.f;
    __syncthreads();
    for (int i=tid;i<NB;i+=BLOCK) wf[i]=0.f;
    __syncthreads();
    ROW4_BEGIN
      if ((int)(u>>20) == bp1){
        bool kk_ok = (!topk_act) || (u > uk) || (u == uk && idx <= idxk);
        if (kk_ok) atomicAdd(&wf[(u>>8)&0xFFFu], expf(x));
      }
    ROW4_END
    __syncthreads();
    suffix_scan_f(wf, tmpf, tid);
    if (tid==0) s_idx = -2;
    __syncthreads();
    for (int i=tid;i<NB;i+=BLOCK){
      float a  = Mab + wf[i];
      float nn = Mab + ((i+1<NB) ? wf[i+1] : 0.f);
      if (a > tgt && nn <= tgt) s_idx = i;
    }
    __syncthreads();
    int bp2;
    if (s_idx >= 0){ bp2 = s_idx; }
    else {
      if (tid==0) s_idx = NB;
      __syncthreads();
      for (int i=tid;i<NB;i+=BLOCK){
        float a  = wf[i];
        float nn = (i+1<NB) ? wf[i+1] : 0.f;
        if (a > nn) atomicMin(&s_idx, i);
      }
      __syncthreads();
      bp2 = (s_idx < NB) ? s_idx : 0;
    }
    const float Mab2 = Mab + ((bp2+1<NB) ? wf[bp2+1] : 0.f);
    __syncthreads();
    if (tid < 256){ wf[tid]=0.f; wu[tid]=0u; }
    __syncthreads();
    const uint32_t top24p = (((uint32_t)bp1)<<12) | (uint32_t)bp2;
    ROW4_BEGIN
      if ((u>>8) == top24p){
        bool kk_ok = (!topk_act) || (u > uk) || (u == uk && idx <= idxk);
        if (kk_ok){
          atomicAdd(&wf[u & 0xFFu], expf(x));
          atomicAdd(&wu[u & 0xFFu], 1u);
        }
      }
    ROW4_END
    __syncthreads();
    if (tid==0){
      float run = 0.f; int b3 = -1; float mgt = 0.f;
      for (int i=255;i>=0;--i){
        float sufn = run; run += wf[i];
        if (Mab2 + run > tgt && Mab2 + sufn <= tgt){ b3 = i; mgt = Mab2 + sufn; break; }
      }
      if (b3 < 0){
        float run2 = 0.f;
        for (int i=255;i>=0;--i){
          if (wu[i] > 0u){ b3 = i; mgt = Mab2 + run2; }
          run2 += wf[i];
        }
        if (b3 < 0){ b3 = 0; mgt = Mab2; }
      }
      const uint32_t upv = (((uint32_t)bp1)<<20) | (((uint32_t)bp2)<<8) | (uint32_t)b3;
      const int ntp = (int)wu[b3];
      const float ev = expf(keyval(upv));
      int t = 0;
      for (int j=1;j<=ntp;j++){
        float before = mgt + (float)(j-1) * ev;
        if (before / Zk <= p) t++; else break;
      }
      if (t < 1) t = 1;
      s_up = upv; s_tp = t; s_ntp = ntp; s_n = 0;
    }
    __syncthreads();
    up = s_up;
    if (s_tp < s_ntp){
      ROW4_BEGIN
        if (u == up){
          bool kk_ok = (!topk_act) || (u > uk) || (u == uk && idx <= idxk);
          if (kk_ok){
            int pos = atomicAdd(&s_n, 1);
            if (pos < NB) wu[pos] = idx;
          }
        }
      ROW4_END
      __syncthreads();
      if (tid==0){
        int n2 = min(s_n, NB);
        int t  = min(s_tp, n2);
        s_idxp = select_tth_smallest(wu, n2, t);
      }
      __syncthreads();
      idxp = s_idxp;
    }
  }

  const float m  = s_m;
  const float Zs = Zk * expf(-m);
  ull best = 0ull;
  ROW4_BEGIN
    bool kk_ok = (!topk_act) || (u > uk) || (u == uk && idx <= idxk);
    bool kp_ok = pall || (u > up) || (u == up && idx <= idxp);
    if (kk_ok && kp_ok){
      float q = (expf(x - m) / Zs) / exp_noise((uint32_t)b * (uint32_t)VV + idx);
      ull pk = (((ull)__float_as_uint(q)) << 32) | (uint32_t)(~idx);
      best = (pk > best) ? pk : best;
    }
  ROW4_END
  red[tid] = best; __syncthreads();
  for (int d=BLOCK/2; d>0; d>>=1){
    if (tid < d){ ull o = red[tid+d]; if (o > red[tid]) red[tid] = o; }
    __syncthreads();
  }
  if (tid==0) out[b] = (int)(~(uint32_t)(red[0] & 0xFFFFFFFFull));
}

extern "C" void kernel_launch(void* const* d_in, const int* in_sizes, int n_in,
                              void* d_out, int out_size, void* d_ws, size_t ws_size,
                              hipStream_t stream) {
  (void)in_sizes; (void)n_in; (void)out_size; (void)d_ws; (void)ws_size;
  const float* logits = (const float*)d_in[0];
  const float* temps  = (const float*)d_in[1];
  const int*   ks     = (const int*)d_in[2];
  const float* ps     = (const float*)d_in[3];
  int* out = (int*)d_out;
  sampler_kernel<<<256, BLOCK, 0, stream>>>(logits, temps, ks, ps, out);
}

// Round 2
// 211.512 us; speedup vs baseline: 1.1167x; 1.1167x over previous
//
#include <hip/hip_runtime.h>
#include <stdint.h>

#define VV 128000
#define BLOCK 1024
#define NB 4096
#define CAP 4096
#define THR 2.0f
#define U0  0xC0000000u   /* fkey(2.0f) */
#define MSEL 2048
#define NSEG 16
#define CAPSEG 320        /* Poisson(182) +10 sigma */
#define F4SEG 2000        /* 32000 float4 / 16 segments */

typedef unsigned long long ull;

__device__ __forceinline__ uint32_t rotl32(uint32_t x, int r){ return (x << r) | (x >> (32 - r)); }

// Bit-exact replica of jax.random.exponential(key(42), (256,128000), f32) at flat
// index f, under jax_threefry_partitionable=True.
__device__ __forceinline__ float exp_noise(uint32_t f){
  const uint32_t ks0 = 0u, ks1 = 42u, ks2 = 0x1BD11BDAu ^ 0u ^ 42u;
  uint32_t x0 = 0u + ks0;
  uint32_t x1 = f + ks1;
#define R1(r) { x0 += x1; x1 = rotl32(x1, r); x1 ^= x0; }
  R1(13) R1(15) R1(26) R1(6)   x0 += ks1; x1 += ks2 + 1u;
  R1(17) R1(29) R1(16) R1(24)  x0 += ks2; x1 += ks0 + 2u;
  R1(13) R1(15) R1(26) R1(6)   x0 += ks0; x1 += ks1 + 3u;
  R1(17) R1(29) R1(16) R1(24)  x0 += ks1; x1 += ks2 + 4u;
  R1(13) R1(15) R1(26) R1(6)   x0 += ks2; x1 += ks0 + 5u;
#undef R1
  uint32_t bits = x0 ^ x1;
  float u = __uint_as_float((bits >> 9) | 0x3F800000u) - 1.0f;
  float e = -log1pf(-u);
  return fmaxf(e, 1e-10f);
}

// ascending-order key: larger float -> larger key (total order; no NaN in input)
__device__ __forceinline__ uint32_t fkey(float x){
  uint32_t u = __float_as_uint(x);
  return u ^ ((u & 0x80000000u) ? 0xFFFFFFFFu : 0x80000000u);
}
__device__ __forceinline__ float keyval(uint32_t k){
  uint32_t bits = (k & 0x80000000u) ? (k ^ 0x80000000u) : ~k;
  return __uint_as_float(bits);
}

// In-place inclusive suffix sum over NB=4096 entries (4 per thread + Hillis-Steele).
__device__ void suffix_scan_u(uint32_t* h, uint32_t* tmp, int tid){
  const int base = tid * 4;
  uint32_t l0=h[base], l1=h[base+1], l2=h[base+2], l3=h[base+3];
  uint32_t s3=l3, s2=l2+s3, s1=l1+s2, s0=l0+s1;
  tmp[tid] = s0; __syncthreads();
  for (int d=1; d<BLOCK; d<<=1){
    uint32_t add = (tid+d<BLOCK) ? tmp[tid+d] : 0u;
    __syncthreads();
    tmp[tid] += add;
    __syncthreads();
  }
  uint32_t E = (tid+1<BLOCK) ? tmp[tid+1] : 0u;
  h[base]=s0+E; h[base+1]=s1+E; h[base+2]=s2+E; h[base+3]=s3+E;
  __syncthreads();
}
__device__ void suffix_scan_f(float* h, float* tmp, int tid){
  const int base = tid * 4;
  float l0=h[base], l1=h[base+1], l2=h[base+2], l3=h[base+3];
  float s3=l3, s2=l2+s3, s1=l1+s2, s0=l0+s1;
  tmp[tid] = s0; __syncthreads();
  for (int d=1; d<BLOCK; d<<=1){
    float add = (tid+d<BLOCK) ? tmp[tid+d] : 0.f;
    __syncthreads();
    tmp[tid] += add;
    __syncthreads();
  }
  float E = (tid+1<BLOCK) ? tmp[tid+1] : 0.f;
  h[base]=s0+E; h[base+1]=s1+E; h[base+2]=s2+E; h[base+3]=s3+E;
  __syncthreads();
}

// tid0-serial: move the t smallest of a[0..n) to front, return t-th smallest.
__device__ uint32_t select_tth_smallest(uint32_t* a, int n, int t){
  for (int i=0;i<t;i++){
    int mi=i; uint32_t mv=a[i];
    for (int j=i+1;j<n;j++) if (a[j]<mv){ mv=a[j]; mi=j; }
    a[mi]=a[i]; a[i]=mv;
  }
  return a[t-1];
}

// bitonic ascending on packed (~key, idx): value desc, idx asc (stable argsort(-x))
__device__ void bitonic_sort(ull* a, int N, int tid){
  for (int len=2; len<=N; len<<=1){
    for (int j=len>>1; j>0; j>>=1){
      for (int i=tid; i<N; i+=BLOCK){
        int l = i ^ j;
        if (l > i){
          ull x = a[i], y = a[l];
          bool asc = ((i & len) == 0);
          if (asc ? (x > y) : (x < y)){ a[i]=y; a[l]=x; }
        }
      }
      __syncthreads();
    }
  }
}

// Raw-key row loop (no division): u = fkey(raw logit).
#define ROW4R_BEGIN \
    for (int c0 = tid; c0 < VV/4; c0 += BLOCK*4){ \
      float4 qv[4]; int cb[4]; bool gv[4]; \
      _Pragma("unroll") \
      for (int t=0;t<4;t++){ int cc = c0 + t*BLOCK; gv[t] = (cc < VV/4); cb[t] = cc*4; if (gv[t]) qv[t] = rp[cc]; } \
      _Pragma("unroll") \
      for (int t=0;t<4;t++) if (gv[t]){ \
        float vs[4] = {qv[t].x, qv[t].y, qv[t].z, qv[t].w}; \
        _Pragma("unroll") \
        for (int j=0;j<4;j++){ \
          uint32_t u = fkey(vs[j]); \
          uint32_t idx = (uint32_t)(cb[t]+j); \
          (void)idx;
#define ROW4R_END } } }

// x-key row loop (exact x = v/T), for the slow (k==0 / overflow) path.
#define ROW4_BEGIN \
    for (int c0 = tid; c0 < VV/4; c0 += BLOCK*4){ \
      float4 qv[4]; int cb[4]; bool gv[4]; \
      _Pragma("unroll") \
      for (int t=0;t<4;t++){ int cc = c0 + t*BLOCK; gv[t] = (cc < VV/4); cb[t] = cc*4; if (gv[t]) qv[t] = rp[cc]; } \
      _Pragma("unroll") \
      for (int t=0;t<4;t++) if (gv[t]){ \
        float xs[4] = {qv[t].x, qv[t].y, qv[t].z, qv[t].w}; \
        _Pragma("unroll") \
        for (int j=0;j<4;j++){ \
          float x = xs[j]/T; \
          uint32_t u = fkey(x); \
          uint32_t idx = (uint32_t)(cb[t]+j); \
          (void)idx;
#define ROW4_END } } }

// ============================================================================
// Kernel A: memory-bound threshold gather. 16 blocks per row, 256 threads.
// Each block owns a fixed [row, seg] chunk of ws — no cross-block atomics.
// Packs candidates as (fkey(v)<<32) | ~idx (desc value, asc idx tiebreak).
// ============================================================================
__global__ __launch_bounds__(256) void gather_kernel(
    const float* __restrict__ logits, ull* __restrict__ g_cand,
    uint32_t* __restrict__ g_cnt)
{
  const int bid = blockIdx.x;
  const int row = bid >> 4, seg = bid & 15;
  const int tid = threadIdx.x;
  const float4* rp = reinterpret_cast<const float4*>(logits + (size_t)row * VV);
  __shared__ ull buf[CAPSEG];
  __shared__ int cnt;
  if (tid==0) cnt = 0;
  __syncthreads();
  const int c1 = (seg+1)*F4SEG;
  for (int c = seg*F4SEG + tid; c < c1; c += 256){
    float4 q = rp[c];
    float vs[4] = {q.x, q.y, q.z, q.w};
    #pragma unroll
    for (int j=0;j<4;j++){
      if (vs[j] >= THR){
        int pos = atomicAdd(&cnt, 1);
        uint32_t idx = (uint32_t)(c*4 + j);
        if (pos < CAPSEG) buf[pos] = (((ull)fkey(vs[j]))<<32) | (ull)(~idx);
      }
    }
  }
  __syncthreads();
  const int n = min(cnt, CAPSEG);
  ull* dst = g_cand + (size_t)row*(NSEG*CAPSEG) + seg*CAPSEG;
  for (int i=tid;i<n;i+=256) dst[i] = buf[i];
  if (tid==0) g_cnt[row*NSEG + seg] = (uint32_t)cnt;
}

// ============================================================================
// Kernel B: per-row selection + sampling from gathered candidates.
// ============================================================================
__global__ __launch_bounds__(BLOCK) void sampler_kernel(
    const float* __restrict__ logits, const float* __restrict__ temps,
    const int* __restrict__ topks, const float* __restrict__ topps,
    int* __restrict__ out, const ull* __restrict__ g_cand,
    const uint32_t* __restrict__ g_cnt, int use_ws)
{
  // Carved shared memory (102400 B):
  //  NEW path: hist u32[4096] @0 (16K), hsuf u32[4096] @16K (16K),
  //            srt2 ull[2048] @32K (16K), wtot u32[16] @48K
  //  OLD fast path: h4 u32[16384] @0 (64K) | cand ull[4096] @0, h2 @32K, sort2 @48K
  //  slow path: S f[4096] @0, wf f[4096] @16K
  //  [64K,80K) wu u32[4096]
  //  [80K,84K) tmpf f[1024]; [84K,88K) tmpu u32[1024];
  //  [88K,92K) ck f[1024];   [92K,100K) red ull[1024]
  // (Overlays are safe: every consumer initializes its region before reading.)
  __shared__ __align__(16) uint8_t SM[102400];
  uint32_t* hist  = (uint32_t*)SM;
  uint32_t* hsuf  = (uint32_t*)(SM + 16*1024);
  ull*      srt2  = (ull*)(SM + 32*1024);
  uint32_t* wtot  = (uint32_t*)(SM + 48*1024);
  uint32_t* h4    = (uint32_t*)SM;
  ull*      cand  = (ull*)SM;
  uint32_t* h2    = (uint32_t*)(SM + 32*1024);
  ull*      sort2 = (ull*)(SM + 48*1024);
  float*    S     = (float*)SM;
  float*    wf    = (float*)(SM + 16*1024);
  uint32_t* wu    = (uint32_t*)(SM + 64*1024);
  float*    tmpf  = (float*)(SM + 80*1024);
  uint32_t* tmpu  = (uint32_t*)(SM + 84*1024);
  float*    ck    = (float*)(SM + 88*1024);
  ull*      red   = (ull*)(SM + 92*1024);

  __shared__ int s_idx, s_n, s_n2, s_tk, s_ntk, s_tp, s_ntp;
  __shared__ uint32_t s_uk, s_idxk, s_up, s_idxp;
  __shared__ float s_m, s_Zk, s_Ztot;
  __shared__ ull s_K0;

  const int b   = blockIdx.x;
  const int tid = threadIdx.x;
  const float T = temps[b];
  const int   k = topks[b];
  const float p = topps[b];
  const float* row = logits + (size_t)b * VV;
  const float4* rp = reinterpret_cast<const float4*>(row);
  const bool topk_act = (k > 0) && (k < VV);
  const bool topp_act = (p > 0.0f) && (p < 1.0f);

  // ============================================================================
  // NEW FAST PATH: candidates from ws (no row streaming) + counting-rank
  // selection (hierarchical suffix scan + bucket scatter, no sort, no O(m) loop).
  // Verified epilogue kept verbatim. Any gate failure -> old verified machinery.
  // ============================================================================
  if (topk_act && use_ws && k <= BLOCK){
    // per-segment counts (uniform across threads; all read same global values)
    int cs[NSEG]; int nf = 0; bool ovf = false;
    const uint32_t* gc = g_cnt + b*NSEG;
    #pragma unroll
    for (int s=0;s<NSEG;s++){
      int c = (int)gc[s];
      if (c > CAPSEG) ovf = true;
      c = min(c, CAPSEG);
      cs[s] = c; nf += c;
    }
    if (!ovf && nf >= k){
      const ull* gcd = g_cand + (size_t)b*(NSEG*CAPSEG);
      // ---- 4096-bin histogram over candidates ----
      for (int i=tid;i<NB;i+=BLOCK) hist[i]=0u;
      __syncthreads();
      for (int s=0;s<NSEG;s++){
        for (int i=tid;i<cs[s];i+=BLOCK){
          uint32_t u2 = (uint32_t)(gcd[s*CAPSEG+i]>>32);
          uint32_t bu = (u2 - U0) >> 12; if (bu > 4095u) bu = 4095u;
          atomicAdd(&hist[bu], 1u);
        }
      }
      __syncthreads();
      // ---- hierarchical suffix scan hist -> hsuf (3 barriers) ----
      const int lane = tid & 63, wid = tid >> 6;
      const int bb = tid*4;
      uint32_t l0=hist[bb], l1=hist[bb+1], l2=hist[bb+2], l3=hist[bb+3];
      uint32_t s3=l3, s2=l2+s3, s1=l1+s2, s0=l0+s1;
      uint32_t v = s0;
      #pragma unroll
      for (int d=1; d<64; d<<=1){ uint32_t o=__shfl_down(v,d); if (lane+d<64) v += o; }
      if (lane==0) wtot[wid] = v;
      const uint32_t wexcl = v - s0;
      __syncthreads();
      if (wid==0){
        uint32_t w = (lane<16) ? wtot[lane] : 0u;
        uint32_t own = w;
        #pragma unroll
        for (int d=1; d<16; d<<=1){ uint32_t o=__shfl_down(w,d); if (lane+d<16) w += o; }
        if (lane<16) wtot[lane] = w - own;   // exclusive suffix over waves
      }
      __syncthreads();
      const uint32_t E = wtot[wid] + wexcl;
      hsuf[bb]=s0+E; hsuf[bb+1]=s1+E; hsuf[bb+2]=s2+E; hsuf[bb+3]=s3+E;
      if (tid==0) s_idx = 0;
      __syncthreads();
      // ---- find cutoff bucket: hsuf[gam] >= k > hsuf[gam+1] ----
      #pragma unroll
      for (int j=0;j<4;j++){
        int i = bb+j;
        uint32_t a  = hsuf[i];
        uint32_t nn = (i < NB-1) ? hsuf[i+1] : 0u;
        if (a >= (uint32_t)k && nn < (uint32_t)k) s_idx = i;
      }
      __syncthreads();
      const int gam = s_idx;
      const int m = (int)hsuf[gam];          // survivors, >= k, exact
      if (m <= MSEL){
        // ---- scatter survivors bucket-descending; hist doubles as cursor ----
        for (int s=0;s<NSEG;s++){
          for (int i=tid;i<cs[s];i+=BLOCK){
            ull e = gcd[s*CAPSEG+i];
            uint32_t u2 = (uint32_t)(e>>32);
            uint32_t bu = (u2 - U0) >> 12; if (bu > 4095u) bu = 4095u;
            if ((int)bu >= gam){
              uint32_t sub  = atomicSub(&hist[bu], 1u) - 1u;
              uint32_t base = (bu < NB-1) ? hsuf[bu+1] : 0u;
              srt2[base + sub] = e;
            }
          }
        }
        __syncthreads();
        // ---- exact ranks: bucket base + within-bucket compares (avg ~1) ----
        ull K0=0ull, K1=0ull; int r0=0, r1=0;
        if (tid < m){
          K0 = srt2[tid];
          uint32_t u2 = (uint32_t)(K0>>32);
          uint32_t bu = (u2 - U0) >> 12; if (bu > 4095u) bu = 4095u;
          uint32_t base = (bu < NB-1) ? hsuf[bu+1] : 0u;
          uint32_t nb = hsuf[bu] - base;
          int r = (int)base;
          for (uint32_t q=0;q<nb;q++) r += (srt2[base+q] > K0);
          r0 = r;
        }
        if (tid+BLOCK < m){
          K1 = srt2[tid+BLOCK];
          uint32_t u2 = (uint32_t)(K1>>32);
          uint32_t bu = (u2 - U0) >> 12; if (bu > 4095u) bu = 4095u;
          uint32_t base = (bu < NB-1) ? hsuf[bu+1] : 0u;
          uint32_t nb = hsuf[bu] - base;
          int r = (int)base;
          for (uint32_t q=0;q<nb;q++) r += (srt2[base+q] > K1);
          r1 = r;
        }
        if (tid < m && r0 == 0)       s_K0 = K0;
        if (tid+BLOCK < m && r1 == 0) s_K0 = K1;
        __syncthreads();
        // ---- verified epilogue (identical association to passing kernel) ----
        const float xm = keyval((uint32_t)(s_K0>>32)) / T;   // row max of x
        float w0 = 0.f, w1 = 0.f;
        if (tid < m && r0 < k)       w0 = expf(keyval((uint32_t)(K0>>32))/T - xm);
        if (tid+BLOCK < m && r1 < k) w1 = expf(keyval((uint32_t)(K1>>32))/T - xm);
        ck[tid] = 0.f;
        __syncthreads();
        if (tid < m && r0 < k)       ck[r0] = w0;
        if (tid+BLOCK < m && r1 < k) ck[r1] = w1;
        __syncthreads();
        for (int d=BLOCK/2; d>0; d>>=1){
          if (tid < d) ck[tid] += ck[tid+d];
          __syncthreads();
        }
        if (tid==0) s_Ztot = ck[0];
        __syncthreads();
        const float Zk = s_Ztot;
        ck[tid] = 0.f;
        __syncthreads();
        if (tid < m && r0 < k)       ck[r0] = w0 / Zk;
        if (tid+BLOCK < m && r1 < k) ck[r1] = w1 / Zk;
        __syncthreads();
        for (int d=1; d<BLOCK; d<<=1){
          float add = (tid >= d) ? ck[tid-d] : 0.f;
          __syncthreads();
          ck[tid] += add;
          __syncthreads();
        }
        tmpu[tid] = (tid < k && ck[tid] <= p) ? 1u : 0u;
        __syncthreads();
        for (int d=BLOCK/2; d>0; d>>=1){
          if (tid < d) tmpu[tid] += tmpu[tid+d];
          __syncthreads();
        }
        int L;
        if (!topp_act) L = k;
        else { int c = (int)tmpu[0]; L = (c >= k) ? k : (c + 1); }
        red[tid] = 0ull;
        __syncthreads();
        if (tid < m && r0 < L){
          uint32_t idx0 = ~(uint32_t)K0;
          float q = w0 / exp_noise((uint32_t)b * (uint32_t)VV + idx0);
          red[r0] = (((ull)__float_as_uint(q)) << 32) | (uint32_t)K0;
        }
        if (tid+BLOCK < m && r1 < L){
          uint32_t idx1 = ~(uint32_t)K1;
          float q = w1 / exp_noise((uint32_t)b * (uint32_t)VV + idx1);
          red[r1] = (((ull)__float_as_uint(q)) << 32) | (uint32_t)K1;
        }
        __syncthreads();
        for (int d=BLOCK/2; d>0; d>>=1){
          if (tid < d){ ull o = red[tid+d]; if (o > red[tid]) red[tid] = o; }
          __syncthreads();
        }
        if (tid==0) out[b] = (int)(~(uint32_t)(red[0] & 0xFFFFFFFFull));
        return;
      }
      __syncthreads();   // m > MSEL: leave overlay safely -> old machinery
    }
  }

  // ==========================================================================
  // OLD FAST PATH (k in [1,1023]) — division-free streaming on raw logit keys.
  // ==========================================================================
  if (topk_act){
    for (int i=tid;i<4*NB;i+=BLOCK) h4[i]=0u;
    __syncthreads();
    ROW4R_BEGIN
      atomicAdd(&h4[((u>>20)<<2) | (uint32_t)(tid&3)], 1u);
    ROW4R_END
    __syncthreads();
    for (int i=tid;i<NB;i+=BLOCK)
      wu[i] = h4[(i<<2)] + h4[(i<<2)|1] + h4[(i<<2)|2] + h4[(i<<2)|3];
    __syncthreads();
    suffix_scan_u(wu, tmpu, tid);   // wu[i] = count of items with bucket >= i
    if (tid==0) s_idx = 0;
    __syncthreads();
    for (int i=tid;i<NB;i+=BLOCK){
      uint32_t a  = wu[i];
      uint32_t nn = (i+1<NB) ? wu[i+1] : 0u;
      if (a >= (uint32_t)k && nn < (uint32_t)k) s_idx = i;
    }
    __syncthreads();
    const uint32_t beta = (uint32_t)s_idx;
    const int n = (int)wu[beta];                          // exact, >= k
    const uint32_t c_above = (beta+1<NB) ? wu[beta+1] : 0u; // exact, < k
    if (n <= CAP){
      if (tid==0) s_n = 0;
      __syncthreads();
      ROW4R_BEGIN
        if ((u>>20) >= beta){
          int pos = atomicAdd(&s_n, 1);
          cand[pos] = (((ull)(~u))<<32) | idx;   // pos < n <= CAP guaranteed
        }
      ROW4R_END
      __syncthreads();
      // ---- prune to <=1024 entries before sorting (integer-exact) ----
      ull* srt; int m;
      if (n <= 1024){ srt = cand; m = n; }
      else {
        for (int i=tid;i<NB;i+=BLOCK) h2[i]=0u;
        __syncthreads();
        for (int i=tid;i<n;i+=BLOCK){
          uint32_t u2 = ~(uint32_t)(cand[i]>>32);
          if ((u2>>20) == beta) atomicAdd(&h2[(u2>>8)&0xFFFu], 1u);
        }
        __syncthreads();
        suffix_scan_u(h2, tmpu, tid);
        const uint32_t kr = (uint32_t)k - c_above;   // >= 1
        if (tid==0) s_idx = 0;
        __syncthreads();
        for (int i=tid;i<NB;i+=BLOCK){
          uint32_t a  = h2[i];
          uint32_t nn = (i+1<NB) ? h2[i+1] : 0u;
          if (a >= kr && nn < kr) s_idx = i;
        }
        __syncthreads();
        const uint32_t gam = (uint32_t)s_idx;
        const int np = (int)(c_above + h2[gam]);     // exact survivors, >= k
        if (np <= 1024){
          if (tid==0) s_n2 = 0;
          __syncthreads();
          const uint32_t cut24 = (beta<<12) | gam;
          for (int i=tid;i<n;i+=BLOCK){
            ull e = cand[i];
            uint32_t u2 = ~(uint32_t)(e>>32);
            if ((u2>>8) >= cut24){
              int pos = atomicAdd(&s_n2, 1);
              sort2[pos] = e;                        // pos < np guaranteed
            }
          }
          __syncthreads();
          srt = sort2; m = np;
        } else { srt = cand; m = n; }                // massive sub-bucket tie: rare
      }
      int N = 2; while (N < m) N <<= 1;
      for (int i=tid;i<N;i+=BLOCK) if (i >= m) srt[i] = 0xFFFFFFFFFFFFFFFFull;
      __syncthreads();
      bitonic_sort(srt, N, tid);
      // ---- exact top-k = first k entries; softmax over them ----
      const int kk = k;
      const float xm = keyval(~(uint32_t)(srt[0]>>32)) / T;   // row max of x
      float w = 0.f; uint32_t myidx = 0u;
      if (tid < kk){
        ull e = srt[tid];
        myidx = (uint32_t)e;
        float xv = keyval(~(uint32_t)(e>>32)) / T;
        w = expf(xv - xm);
      }
      ck[tid] = w; __syncthreads();
      for (int d=BLOCK/2; d>0; d>>=1){
        if (tid < d) ck[tid] += ck[tid+d];
        __syncthreads();
      }
      if (tid==0) s_Ztot = ck[0];
      __syncthreads();
      const float Zk = s_Ztot;
      // inclusive cumsum of probs; count cumsum <= p among first kk
      ck[tid] = w / Zk; __syncthreads();
      for (int d=1; d<BLOCK; d<<=1){
        float add = (tid >= d) ? ck[tid-d] : 0.f;
        __syncthreads();
        ck[tid] += add;
        __syncthreads();
      }
      tmpu[tid] = (tid < kk && ck[tid] <= p) ? 1u : 0u;
      __syncthreads();
      for (int d=BLOCK/2; d>0; d>>=1){
        if (tid < d) tmpu[tid] += tmpu[tid+d];
        __syncthreads();
      }
      int L;
      if (!topp_act) L = kk;
      else { int c = (int)tmpu[0]; L = (c >= kk) ? kk : (c + 1); }
      // Gumbel-race argmax over first L: argmax w_i / e_i (scale-invariant)
      ull best = 0ull;
      if (tid < L){
        float q = w / exp_noise((uint32_t)b * (uint32_t)VV + myidx);
        best = (((ull)__float_as_uint(q)) << 32) | (uint32_t)(~myidx);
      }
      red[tid] = best; __syncthreads();
      for (int d=BLOCK/2; d>0; d>>=1){
        if (tid < d){ ull o = red[tid+d]; if (o > red[tid]) red[tid] = o; }
        __syncthreads();
      }
      if (tid==0) out[b] = (int)(~(uint32_t)(red[0] & 0xFFFFFFFFull));
      return;
    }
    __syncthreads();  // n > CAP (statistically never) -> slow path
  }

  // ============================================================================
  // SLOW PATH (k==0, or fast-path overflow): round-3 verified radix machinery
  // ============================================================================
  for (int i=tid;i<NB;i+=BLOCK){ S[i]=0.f; wu[i]=0u; }
  __syncthreads();
  float lmax = -3.4e38f;
  ROW4_BEGIN
    lmax = fmaxf(lmax, x);
    atomicAdd(&wu[u>>20], 1u);
    atomicAdd(&S[u>>20], expf(x));
  ROW4_END
  tmpf[tid] = lmax; __syncthreads();
  for (int d=BLOCK/2; d>0; d>>=1){
    if (tid < d) tmpf[tid] = fmaxf(tmpf[tid], tmpf[tid+d]);
    __syncthreads();
  }
  if (tid==0) s_m = tmpf[0];
  __syncthreads();
  suffix_scan_u(wu, tmpu, tid);
  suffix_scan_f(S,  tmpf, tid);

  uint32_t uk = 0u, idxk = 0xFFFFFFFFu;
  int bk1 = -1;
  if (topk_act){
    if (tid==0) s_idx = 0;
    __syncthreads();
    for (int i=tid;i<NB;i+=BLOCK){
      uint32_t a  = wu[i];
      uint32_t nn = (i+1<NB) ? wu[i+1] : 0u;
      if (a >= (uint32_t)k && nn < (uint32_t)k) s_idx = i;
    }
    __syncthreads();
    bk1 = s_idx;
    const uint32_t c_above1 = (bk1+1<NB) ? wu[bk1+1] : 0u;
    const float    M_above1 = (bk1+1<NB) ? S[bk1+1]  : 0.f;
    __syncthreads();
    for (int i=tid;i<NB;i+=BLOCK){ wu[i]=0u; wf[i]=0.f; }
    __syncthreads();
    ROW4_BEGIN
      if ((int)(u>>20) == bk1){
        atomicAdd(&wu[(u>>8)&0xFFFu], 1u);
        atomicAdd(&wf[(u>>8)&0xFFFu], expf(x));
      }
    ROW4_END
    __syncthreads();
    suffix_scan_u(wu, tmpu, tid);
    suffix_scan_f(wf, tmpf, tid);
    if (tid==0) s_idx = 0;
    __syncthreads();
    for (int i=tid;i<NB;i+=BLOCK){
      uint32_t a  = c_above1 + wu[i];
      uint32_t nn = c_above1 + ((i+1<NB) ? wu[i+1] : 0u);
      if (a >= (uint32_t)k && nn < (uint32_t)k) s_idx = i;
    }
    __syncthreads();
    const int bk2 = s_idx;
    const uint32_t c_above2 = c_above1 + ((bk2+1<NB) ? wu[bk2+1] : 0u);
    const float    M_above2 = M_above1 + ((bk2+1<NB) ? wf[bk2+1] : 0.f);
    __syncthreads();
    if (tid < 256){ wu[tid]=0u; wf[tid]=0.f; }
    __syncthreads();
    const uint32_t top24k = (((uint32_t)bk1)<<12) | (uint32_t)bk2;
    ROW4_BEGIN
      if ((u>>8) == top24k){
        atomicAdd(&wu[u & 0xFFu], 1u);
        atomicAdd(&wf[u & 0xFFu], expf(x));
      }
    ROW4_END
    __syncthreads();
    if (tid==0){
      uint32_t r = 0u; float mr = 0.f; int b3 = 0;
      for (int i=255;i>=0;--i){
        if (c_above2 + r + wu[i] >= (uint32_t)k){ b3 = i; break; }
        r += wu[i]; mr += wf[i];
      }
      const uint32_t cgt = c_above2 + r;
      const float mgt = M_above2 + mr;
      const int nt = (int)wu[b3];
      const int tk = k - (int)cgt;
      s_uk  = (((uint32_t)bk1)<<20) | (((uint32_t)bk2)<<8) | (uint32_t)b3;
      s_tk  = tk; s_ntk = nt;
      s_Zk  = mgt + (float)tk * expf(keyval(s_uk));
      s_n   = 0;
    }
    __syncthreads();
    uk = s_uk;
    if (s_tk < s_ntk){
      ROW4_BEGIN
        if (u == uk){
          int pos = atomicAdd(&s_n, 1);
          if (pos < NB) wu[pos] = idx;
        }
      ROW4_END
      __syncthreads();
      if (tid==0){
        int n2 = min(s_n, NB);
        int t  = min(s_tk, n2);
        s_idxk = select_tth_smallest(wu, n2, t);
      }
      __syncthreads();
      idxk = s_idxk;
    }
  }
  const float Zk = topk_act ? s_Zk : S[0];

  uint32_t up = 0u, idxp = 0xFFFFFFFFu;
  const float tgt = p * Zk;
  const bool pall = (!topp_act) || (tgt >= Zk);
  if (!pall){
    if (tid==0) s_idx = -2;
    __syncthreads();
    for (int i=tid;i<NB;i+=BLOCK){
      if (i > bk1){
        float a  = S[i];
        float nn = (i+1<NB) ? S[i+1] : 0.f;
        if (a > tgt && nn <= tgt) s_idx = i;
      }
    }
    __syncthreads();
    int bp1 = (s_idx >= 0) ? s_idx : bk1;
    if (bp1 < 0) bp1 = 0;
    const float Mab = (bp1+1<NB) ? S[bp1+1] : 0.f;
    __syncthreads();
    for (int i=tid;i<NB;i+=BLOCK) wf[i]=0.f;
    __syncthreads();
    ROW4_BEGIN
      if ((int)(u>>20) == bp1){
        bool kk_ok = (!topk_act) || (u > uk) || (u == uk && idx <= idxk);
        if (kk_ok) atomicAdd(&wf[(u>>8)&0xFFFu], expf(x));
      }
    ROW4_END
    __syncthreads();
    suffix_scan_f(wf, tmpf, tid);
    if (tid==0) s_idx = -2;
    __syncthreads();
    for (int i=tid;i<NB;i+=BLOCK){
      float a  = Mab + wf[i];
      float nn = Mab + ((i+1<NB) ? wf[i+1] : 0.f);
      if (a > tgt && nn <= tgt) s_idx = i;
    }
    __syncthreads();
    int bp2;
    if (s_idx >= 0){ bp2 = s_idx; }
    else {
      if (tid==0) s_idx = NB;
      __syncthreads();
      for (int i=tid;i<NB;i+=BLOCK){
        float a  = wf[i];
        float nn = (i+1<NB) ? wf[i+1] : 0.f;
        if (a > nn) atomicMin(&s_idx, i);
      }
      __syncthreads();
      bp2 = (s_idx < NB) ? s_idx : 0;
    }
    const float Mab2 = Mab + ((bp2+1<NB) ? wf[bp2+1] : 0.f);
    __syncthreads();
    if (tid < 256){ wf[tid]=0.f; wu[tid]=0u; }
    __syncthreads();
    const uint32_t top24p = (((uint32_t)bp1)<<12) | (uint32_t)bp2;
    ROW4_BEGIN
      if ((u>>8) == top24p){
        bool kk_ok = (!topk_act) || (u > uk) || (u == uk && idx <= idxk);
        if (kk_ok){
          atomicAdd(&wf[u & 0xFFu], expf(x));
          atomicAdd(&wu[u & 0xFFu], 1u);
        }
      }
    ROW4_END
    __syncthreads();
    if (tid==0){
      float run = 0.f; int b3 = -1; float mgt = 0.f;
      for (int i=255;i>=0;--i){
        float sufn = run; run += wf[i];
        if (Mab2 + run > tgt && Mab2 + sufn <= tgt){ b3 = i; mgt = Mab2 + sufn; break; }
      }
      if (b3 < 0){
        float run2 = 0.f;
        for (int i=255;i>=0;--i){
          if (wu[i] > 0u){ b3 = i; mgt = Mab2 + run2; }
          run2 += wf[i];
        }
        if (b3 < 0){ b3 = 0; mgt = Mab2; }
      }
      const uint32_t upv = (((uint32_t)bp1)<<20) | (((uint32_t)bp2)<<8) | (uint32_t)b3;
      const int ntp = (int)wu[b3];
      const float ev = expf(keyval(upv));
      int t = 0;
      for (int j=1;j<=ntp;j++){
        float before = mgt + (float)(j-1) * ev;
        if (before / Zk <= p) t++; else break;
      }
      if (t < 1) t = 1;
      s_up = upv; s_tp = t; s_ntp = ntp; s_n = 0;
    }
    __syncthreads();
    up = s_up;
    if (s_tp < s_ntp){
      ROW4_BEGIN
        if (u == up){
          bool kk_ok = (!topk_act) || (u > uk) || (u == uk && idx <= idxk);
          if (kk_ok){
            int pos = atomicAdd(&s_n, 1);
            if (pos < NB) wu[pos] = idx;
          }
        }
      ROW4_END
      __syncthreads();
      if (tid==0){
        int n2 = min(s_n, NB);
        int t  = min(s_tp, n2);
        s_idxp = select_tth_smallest(wu, n2, t);
      }
      __syncthreads();
      idxp = s_idxp;
    }
  }

  const float m  = s_m;
  const float Zs = Zk * expf(-m);
  ull best = 0ull;
  ROW4_BEGIN
    bool kk_ok = (!topk_act) || (u > uk) || (u == uk && idx <= idxk);
    bool kp_ok = pall || (u > up) || (u == up && idx <= idxp);
    if (kk_ok && kp_ok){
      float q = (expf(x - m) / Zs) / exp_noise((uint32_t)b * (uint32_t)VV + idx);
      ull pk = (((ull)__float_as_uint(q)) << 32) | (uint32_t)(~idx);
      best = (pk > best) ? pk : best;
    }
  ROW4_END
  red[tid] = best; __syncthreads();
  for (int d=BLOCK/2; d>0; d>>=1){
    if (tid < d){ ull o = red[tid+d]; if (o > red[tid]) red[tid] = o; }
    __syncthreads();
  }
  if (tid==0) out[b] = (int)(~(uint32_t)(red[0] & 0xFFFFFFFFull));
}

extern "C" void kernel_launch(void* const* d_in, const int* in_sizes, int n_in,
                              void* d_out, int out_size, void* d_ws, size_t ws_size,
                              hipStream_t stream) {
  (void)in_sizes; (void)n_in; (void)out_size;
  const float* logits = (const float*)d_in[0];
  const float* temps  = (const float*)d_in[1];
  const int*   ks     = (const int*)d_in[2];
  const float* ps     = (const float*)d_in[3];
  int* out = (int*)d_out;

  const size_t cnt_bytes  = 256 * NSEG * sizeof(uint32_t);          // 16 KB
  const size_t cand_bytes = (size_t)256 * NSEG * CAPSEG * sizeof(ull); // ~10.5 MB
  const size_t need = cnt_bytes + cand_bytes;

  uint32_t* g_cnt  = (uint32_t*)d_ws;
  ull*      g_cand = (ull*)((uint8_t*)d_ws + cnt_bytes);
  const int use_ws = (d_ws != nullptr && ws_size >= need) ? 1 : 0;

  if (use_ws)
    gather_kernel<<<256*NSEG, 256, 0, stream>>>(logits, g_cand, g_cnt);
  sampler_kernel<<<256, BLOCK, 0, stream>>>(logits, temps, ks, ps, out,
                                            g_cand, g_cnt, use_ws);
}